// Round 8
// baseline (20893.193 us; speedup 1.0000x reference)
//
#include <hip/hip_runtime.h>
#include <cstdint>

#define SQ 4096
#define FD 256
#define HD 512
#define GD 2048

// workspace layout (float elements)
#define WS_X       0                         // x [4096][512]
#define WS_XPROJ   (WS_X + SQ*HD)            // xproj [2][4096][2048]
#define WS_WT      (WS_XPROJ + 2*SQ*GD)      // conv_w transposed [2][256][256]
#define WS_LINT    (WS_WT + 2*FD*FD)         // lin_w transposed [256][256]
#define WS_SYNC    (WS_LINT + FD*FD)         // payload u64[2][2][512] @64B pitch = 128 KB

typedef __attribute__((ext_vector_type(4))) float f32x4;
typedef unsigned long long u64;

__device__ __forceinline__ float sigf(float x) { return 1.f / (1.f + __expf(-x)); }
__device__ __forceinline__ float tanhf_fast(float x) {
  float xx = fminf(15.f, fmaxf(-15.f, x));
  float e = __expf(2.f * xx);
  return (e - 1.f) * __frcp_rn(e + 1.f);
}

#define REP16(M) M(0)M(1)M(2)M(3)M(4)M(5)M(6)M(7)M(8)M(9)M(10)M(11)M(12)M(13)M(14)M(15)

// ---------------- prep: transpose small weights, zero sync payload ----------------
__global__ __launch_bounds__(256) void prep_kernel(const float* __restrict__ conv_w,
                                                   const float* __restrict__ lin_w,
                                                   float* __restrict__ Wt,
                                                   float* __restrict__ linT,
                                                   float* __restrict__ sync) {
  int n = blockIdx.x * 256 + threadIdx.x;
  if (n < 32768) sync[n] = 0.f;              // 128 KB payload (tags := 0)
  if (n < 2 * FD * FD) {
    int o = n & 255, f = (n >> 8) & 255, k = n >> 16;
    Wt[n] = conv_w[o * 512 + k * 256 + f];   // Wt[k][f][o]
  } else {
    int m = n - 2 * FD * FD;
    int o = m & 255, f = m >> 8;
    linT[m] = lin_w[o * 256 + f];            // linT[f][o]
  }
}

// ---------------- char CNN + concat into x ----------------
__global__ __launch_bounds__(256) void charcnn_kernel(const float* __restrict__ wemb,
    const int* __restrict__ cidx, const float* __restrict__ cemb,
    const float* __restrict__ Wt, const float* __restrict__ conv_b,
    const float* __restrict__ linT, const float* __restrict__ lin_b,
    float* __restrict__ x) {
  __shared__ float ceT[256][20];
  __shared__ float pooled[256];
  int s = blockIdx.x, o = threadIdx.x;
  #pragma unroll
  for (int l = 0; l < 16; ++l) {
    int idx = cidx[s * 16 + l];
    ceT[o][l] = cemb[idx * 256 + o];
  }
  __syncthreads();
  float acc[15];
  float cb = conv_b[o];
  #pragma unroll
  for (int l = 0; l < 15; ++l) acc[l] = cb;
  for (int f = 0; f < 256; ++f) {
    float w0 = Wt[f * 256 + o];
    float w1 = Wt[65536 + f * 256 + o];
    float4 ca = *(const float4*)&ceT[f][0];
    float4 cv = *(const float4*)&ceT[f][4];
    float4 cc = *(const float4*)&ceT[f][8];
    float4 cd = *(const float4*)&ceT[f][12];
    float c[16] = {ca.x, ca.y, ca.z, ca.w, cv.x, cv.y, cv.z, cv.w,
                   cc.x, cc.y, cc.z, cc.w, cd.x, cd.y, cd.z, cd.w};
    #pragma unroll
    for (int l = 0; l < 15; ++l) acc[l] += c[l] * w0 + c[l + 1] * w1;
  }
  float m = 0.f;
  #pragma unroll
  for (int l = 0; l < 15; ++l) m = fmaxf(m, acc[l]);
  pooled[o] = m;
  __syncthreads();
  float a2 = lin_b[o];
  for (int f = 0; f < 256; f += 4) {
    float4 p = *(const float4*)&pooled[f];
    a2 += p.x * linT[(f + 0) * 256 + o] + p.y * linT[(f + 1) * 256 + o]
        + p.z * linT[(f + 2) * 256 + o] + p.w * linT[(f + 3) * 256 + o];
  }
  x[(size_t)s * 512 + o] = wemb[(size_t)s * 256 + o];
  x[(size_t)s * 512 + 256 + o] = a2;
}

// ---------------- input projection GEMM ----------------
__global__ __launch_bounds__(256) void xproj_kernel(const float* __restrict__ x,
    const float* __restrict__ Wih_f, const float* __restrict__ Wih_r,
    const float* __restrict__ bih_f, const float* __restrict__ bhh_f,
    const float* __restrict__ bih_r, const float* __restrict__ bhh_r,
    float* __restrict__ xproj) {
  __shared__ float As[64][33];
  __shared__ float Bs[64][33];
  int dir = blockIdx.z;
  const float* B  = dir ? Wih_r : Wih_f;
  const float* b1 = dir ? bih_r : bih_f;
  const float* b2 = dir ? bhh_r : bhh_f;
  int m0 = blockIdx.x * 64, n0 = blockIdx.y * 64;
  int tid = threadIdx.x, tx = tid & 15, ty = tid >> 4;
  float acc[4][4];
  #pragma unroll
  for (int j = 0; j < 4; ++j) {
    float bias = b1[n0 + tx * 4 + j] + b2[n0 + tx * 4 + j];
    #pragma unroll
    for (int i = 0; i < 4; ++i) acc[i][j] = bias;
  }
  int lc = tid & 31, lr0 = tid >> 5;
  for (int k0 = 0; k0 < 512; k0 += 32) {
    #pragma unroll
    for (int i = 0; i < 8; ++i) {
      As[lr0 + 8 * i][lc] = x[(size_t)(m0 + lr0 + 8 * i) * 512 + k0 + lc];
      Bs[lr0 + 8 * i][lc] = B[(size_t)(n0 + lr0 + 8 * i) * 512 + k0 + lc];
    }
    __syncthreads();
    #pragma unroll
    for (int kk = 0; kk < 32; ++kk) {
      float a0 = As[ty * 4 + 0][kk], a1 = As[ty * 4 + 1][kk];
      float a2 = As[ty * 4 + 2][kk], a3 = As[ty * 4 + 3][kk];
      float q0 = Bs[tx * 4 + 0][kk], q1 = Bs[tx * 4 + 1][kk];
      float q2 = Bs[tx * 4 + 2][kk], q3 = Bs[tx * 4 + 3][kk];
      acc[0][0] += a0 * q0; acc[0][1] += a0 * q1; acc[0][2] += a0 * q2; acc[0][3] += a0 * q3;
      acc[1][0] += a1 * q0; acc[1][1] += a1 * q1; acc[1][2] += a1 * q2; acc[1][3] += a1 * q3;
      acc[2][0] += a2 * q0; acc[2][1] += a2 * q1; acc[2][2] += a2 * q2; acc[2][3] += a2 * q3;
      acc[3][0] += a3 * q0; acc[3][1] += a3 * q1; acc[3][2] += a3 * q2; acc[3][3] += a3 * q3;
    }
    __syncthreads();
  }
  size_t base = (size_t)dir * SQ * GD;
  #pragma unroll
  for (int i = 0; i < 4; ++i) {
    float4 v = make_float4(acc[i][0], acc[i][1], acc[i][2], acc[i][3]);
    *(float4*)&xproj[base + (size_t)(m0 + ty * 4 + i) * GD + n0 + tx * 4] = v;
  }
}

// ---------------- persistent bidirectional LSTM recurrence ----------------
// 64 blocks: 0..31 fwd, 32..63 rev; block owns 16 h (64 Whh rows = 128 KB,
// staged in LDS -- weights NEVER touch L2 in the loop; per-step each thread
// prefetches its 16 f32x4 from LDS before the poll, consumes after barrier).
// Weight chunks XOR-swizzled by s=gate+4*jl -> both staging reads and GEMV
// prefetch hit the 8-cy ds_read_b128 floor. h LDS quarters padded to 66
// floats -> broadcast + conflict-free.
// h exchange: ONE u64 per h-index per slot: (tag<<32)|h_bits, agent-scope
// (proven r4 path), 64B pitch (one line per word -> 32 pollers/line).
// Double-buffered slots; exact tag match; r4 overwrite-safety proof holds.
__global__ __launch_bounds__(512, 2) void lstm_kernel(const float* __restrict__ xproj,
    const float* __restrict__ Whh_f, const float* __restrict__ Whh_r,
    u64* __restrict__ payu, float* __restrict__ out) {
  __shared__ float wlds[64 * 512];   // 128 KB weight slice
  __shared__ float hl[2][8 * 66];    // double-buffered h, quarter pitch 66
  int dir = blockIdx.x >> 5;
  int wid = blockIdx.x & 31;
  int hbase = wid * 16;
  int tid = threadIdx.x;
  int w = tid >> 6, l = tid & 63;
  int jl = l >> 5, gate = (l >> 3) & 3, kq = l & 7;
  int j = w * 2 + jl;                     // block-local h 0..15
  int lr = gate * 16 + j;                 // local row 0..63
  int Rrow = (gate << 9) + hbase + j;     // global gate row
  int s = gate + (jl << 2);               // bank swizzle 0..7 per (gate,jl)
  const float* Whh = dir ? Whh_r : Whh_f;
  const float* xp = xproj + (size_t)dir * SQ * GD;

  // stage W slice into LDS (one-time): logical chunk i at phys (i^s)
  f32x4* wl4 = (f32x4*)wlds;
  int pbase = lr * 128 + kq * 16;
  {
    const f32x4* gsrc = (const f32x4*)(Whh + (size_t)Rrow * 512 + kq * 64);
    #pragma unroll
    for (int i = 0; i < 16; ++i) wl4[pbase + (i ^ s)] = gsrc[i];
  }

  u64* mypay = payu + (size_t)dir * 8192;      // [slot][512]@8u64 pitch
  const u64* rd0 = mypay + (size_t)tid * 8;
  const u64* rd1 = mypay + 4096 + (size_t)tid * 8;
  u64* wr0 = mypay + (size_t)(hbase + j) * 8;
  u64* wr1 = mypay + 4096 + (size_t)(hbase + j) * 8;

  const bool gl = (l & 31) == 0;               // gate lane (gate=0,kq=0)
  const int hwoff = w * 66 + l;                // h LDS slot for h-index tid
  const int base = l & 32;
  float cst = 0.f, hlast = 0.f;

  for (int t = 0; t < SQ; ++t) {
    int p = dir ? (SQ - 1 - t) : t;
    float xval = 0.f;
    if (kq == 0) xval = xp[(size_t)p * GD + Rrow];   // issued early, hidden
    // prefetch weights from LDS (conflict-free; overlaps the poll)
#define PFW(i) f32x4 w##i = wl4[pbase + (i ^ s)];
    REP16(PFW)
#undef PFW
    float* hbuf = hl[t & 1];
    if (t == 0) {
      hbuf[hwoff] = 0.f;
    } else {
      const u64* src = ((t - 1) & 1) ? rd1 : rd0;
      unsigned tg = (unsigned)t;
      u64 v;
      do { v = __hip_atomic_load(src, __ATOMIC_RELAXED, __HIP_MEMORY_SCOPE_AGENT); }
      while ((unsigned)(v >> 32) != tg);
      hbuf[hwoff] = __uint_as_float((unsigned)v);
    }
    __syncthreads();                             // h ready (sole barrier; also
                                                 // covers one-time W staging)
    const f32x4* hq4 = (const f32x4*)&hbuf[kq * 66];
    float a0 = 0.f, a1 = 0.f, a2 = 0.f, a3 = 0.f;
#define GST(i) { f32x4 hh = hq4[i]; \
    a0 = fmaf(w##i[0], hh[0], a0); a1 = fmaf(w##i[1], hh[1], a1); \
    a2 = fmaf(w##i[2], hh[2], a2); a3 = fmaf(w##i[3], hh[3], a3); }
    REP16(GST)
#undef GST
    float acc = (a0 + a1) + (a2 + a3);
    acc += __shfl_xor(acc, 1);                   // kq reduce (8 lanes)
    acc += __shfl_xor(acc, 2);
    acc += __shfl_xor(acc, 4);
    float gx = acc + xval;                       // valid in kq==0 lanes
    float sI = __shfl(gx, base);                 // in-wave gate gather
    float sF = __shfl(gx, base + 8);
    float sG = __shfl(gx, base + 16);
    float sO = __shfl(gx, base + 24);
    if (gl) {
      float c = sigf(sF) * cst + sigf(sI) * tanhf_fast(sG);
      float hval = sigf(sO) * tanhf_fast(c);
      cst = c; hlast = hval;
      u64 word = ((u64)(unsigned)(t + 1) << 32) | __float_as_uint(hval);
      __hip_atomic_store((t & 1) ? wr1 : wr0, word,
                         __ATOMIC_RELAXED, __HIP_MEMORY_SCOPE_AGENT);
      out[(size_t)p * 1024 + dir * 512 + hbase + j] = hval;
    }
    // h double-buffer + block barrier bound skew to 1 phase -> safe.
  }
  if (gl) {
    size_t OH = (size_t)SQ * 1024;
    out[OH + dir * 512 + hbase + j] = hlast;     // hidden
    out[OH + 1024 + dir * 512 + hbase + j] = cst; // cell
  }
}

extern "C" void kernel_launch(void* const* d_in, const int* in_sizes, int n_in,
                              void* d_out, int out_size, void* d_ws, size_t ws_size,
                              hipStream_t stream) {
  const float* wemb   = (const float*)d_in[0];
  const int*   cidx   = (const int*)d_in[1];
  const float* cemb   = (const float*)d_in[2];
  const float* conv_w = (const float*)d_in[3];
  const float* conv_b = (const float*)d_in[4];
  const float* lin_w  = (const float*)d_in[5];
  const float* lin_b  = (const float*)d_in[6];
  const float* Wih_f  = (const float*)d_in[7];
  const float* Whh_f  = (const float*)d_in[8];
  const float* bih_f  = (const float*)d_in[9];
  const float* bhh_f  = (const float*)d_in[10];
  const float* Wih_r  = (const float*)d_in[11];
  const float* Whh_r  = (const float*)d_in[12];
  const float* bih_r  = (const float*)d_in[13];
  const float* bhh_r  = (const float*)d_in[14];
  float* out = (float*)d_out;
  float* ws = (float*)d_ws;
  float* x     = ws + WS_X;
  float* xproj = ws + WS_XPROJ;
  float* Wt    = ws + WS_WT;
  float* linT  = ws + WS_LINT;
  float* sync  = ws + WS_SYNC;

  prep_kernel<<<768, 256, 0, stream>>>(conv_w, lin_w, Wt, linT, sync);
  charcnn_kernel<<<SQ, 256, 0, stream>>>(wemb, cidx, cemb, Wt, conv_b, linT, lin_b, x);
  xproj_kernel<<<dim3(64, 32, 2), 256, 0, stream>>>(x, Wih_f, Wih_r, bih_f, bhh_f, bih_r, bhh_r, xproj);
  lstm_kernel<<<64, 512, 0, stream>>>(xproj, Whh_f, Whh_r, (u64*)sync, out);
}

// Round 9
// 12520.510 us; speedup vs baseline: 1.6687x; 1.6687x over previous
//
#include <hip/hip_runtime.h>
#include <cstdint>

#define SQ 4096
#define FD 256
#define HD 512
#define GD 2048

// workspace layout (float elements)
#define WS_X       0                         // x [4096][512]
#define WS_XPROJ   (WS_X + SQ*HD)            // xproj [2][4096][2048]
#define WS_WT      (WS_XPROJ + 2*SQ*GD)      // conv_w transposed [2][256][256]
#define WS_LINT    (WS_WT + 2*FD*FD)         // lin_w transposed [256][256]
#define WS_SYNC    (WS_LINT + FD*FD)         // payload: u64[2 dir][2 slot][512] = 16 KB

typedef __attribute__((ext_vector_type(4))) float f32x4;
typedef unsigned long long u64;

__device__ __forceinline__ float sigf(float x) { return 1.f / (1.f + __expf(-x)); }

#define REP32(M) M(0)M(1)M(2)M(3)M(4)M(5)M(6)M(7)M(8)M(9)M(10)M(11)M(12)M(13)M(14)M(15) \
                 M(16)M(17)M(18)M(19)M(20)M(21)M(22)M(23)M(24)M(25)M(26)M(27)M(28)M(29)M(30)M(31)

// ---------------- prep: transpose small weights, zero sync payload ----------------
__global__ __launch_bounds__(256) void prep_kernel(const float* __restrict__ conv_w,
                                                   const float* __restrict__ lin_w,
                                                   float* __restrict__ Wt,
                                                   float* __restrict__ linT,
                                                   float* __restrict__ sync) {
  int n = blockIdx.x * 256 + threadIdx.x;
  if (n < 4096) sync[n] = 0.f;               // 16 KB payload (tags := 0)
  if (n < 2 * FD * FD) {
    int o = n & 255, f = (n >> 8) & 255, k = n >> 16;
    Wt[n] = conv_w[o * 512 + k * 256 + f];   // Wt[k][f][o]
  } else {
    int m = n - 2 * FD * FD;
    int o = m & 255, f = m >> 8;
    linT[m] = lin_w[o * 256 + f];            // linT[f][o]
  }
}

// ---------------- char CNN + concat into x ----------------
__global__ __launch_bounds__(256) void charcnn_kernel(const float* __restrict__ wemb,
    const int* __restrict__ cidx, const float* __restrict__ cemb,
    const float* __restrict__ Wt, const float* __restrict__ conv_b,
    const float* __restrict__ linT, const float* __restrict__ lin_b,
    float* __restrict__ x) {
  __shared__ float ceT[256][20];
  __shared__ float pooled[256];
  int s = blockIdx.x, o = threadIdx.x;
  #pragma unroll
  for (int l = 0; l < 16; ++l) {
    int idx = cidx[s * 16 + l];
    ceT[o][l] = cemb[idx * 256 + o];
  }
  __syncthreads();
  float acc[15];
  float cb = conv_b[o];
  #pragma unroll
  for (int l = 0; l < 15; ++l) acc[l] = cb;
  for (int f = 0; f < 256; ++f) {
    float w0 = Wt[f * 256 + o];
    float w1 = Wt[65536 + f * 256 + o];
    float4 ca = *(const float4*)&ceT[f][0];
    float4 cv = *(const float4*)&ceT[f][4];
    float4 cc = *(const float4*)&ceT[f][8];
    float4 cd = *(const float4*)&ceT[f][12];
    float c[16] = {ca.x, ca.y, ca.z, ca.w, cv.x, cv.y, cv.z, cv.w,
                   cc.x, cc.y, cc.z, cc.w, cd.x, cd.y, cd.z, cd.w};
    #pragma unroll
    for (int l = 0; l < 15; ++l) acc[l] += c[l] * w0 + c[l + 1] * w1;
  }
  float m = 0.f;
  #pragma unroll
  for (int l = 0; l < 15; ++l) m = fmaxf(m, acc[l]);
  pooled[o] = m;
  __syncthreads();
  float a2 = lin_b[o];
  for (int f = 0; f < 256; f += 4) {
    float4 p = *(const float4*)&pooled[f];
    a2 += p.x * linT[(f + 0) * 256 + o] + p.y * linT[(f + 1) * 256 + o]
        + p.z * linT[(f + 2) * 256 + o] + p.w * linT[(f + 3) * 256 + o];
  }
  x[(size_t)s * 512 + o] = wemb[(size_t)s * 256 + o];
  x[(size_t)s * 512 + 256 + o] = a2;
}

// ---------------- input projection GEMM ----------------
__global__ __launch_bounds__(256) void xproj_kernel(const float* __restrict__ x,
    const float* __restrict__ Wih_f, const float* __restrict__ Wih_r,
    const float* __restrict__ bih_f, const float* __restrict__ bhh_f,
    const float* __restrict__ bih_r, const float* __restrict__ bhh_r,
    float* __restrict__ xproj) {
  __shared__ float As[64][33];
  __shared__ float Bs[64][33];
  int dir = blockIdx.z;
  const float* B  = dir ? Wih_r : Wih_f;
  const float* b1 = dir ? bih_r : bih_f;
  const float* b2 = dir ? bhh_r : bhh_f;
  int m0 = blockIdx.x * 64, n0 = blockIdx.y * 64;
  int tid = threadIdx.x, tx = tid & 15, ty = tid >> 4;
  float acc[4][4];
  #pragma unroll
  for (int j = 0; j < 4; ++j) {
    float bias = b1[n0 + tx * 4 + j] + b2[n0 + tx * 4 + j];
    #pragma unroll
    for (int i = 0; i < 4; ++i) acc[i][j] = bias;
  }
  int lc = tid & 31, lr0 = tid >> 5;
  for (int k0 = 0; k0 < 512; k0 += 32) {
    #pragma unroll
    for (int i = 0; i < 8; ++i) {
      As[lr0 + 8 * i][lc] = x[(size_t)(m0 + lr0 + 8 * i) * 512 + k0 + lc];
      Bs[lr0 + 8 * i][lc] = B[(size_t)(n0 + lr0 + 8 * i) * 512 + k0 + lc];
    }
    __syncthreads();
    #pragma unroll
    for (int kk = 0; kk < 32; ++kk) {
      float a0 = As[ty * 4 + 0][kk], a1 = As[ty * 4 + 1][kk];
      float a2 = As[ty * 4 + 2][kk], a3 = As[ty * 4 + 3][kk];
      float q0 = Bs[tx * 4 + 0][kk], q1 = Bs[tx * 4 + 1][kk];
      float q2 = Bs[tx * 4 + 2][kk], q3 = Bs[tx * 4 + 3][kk];
      acc[0][0] += a0 * q0; acc[0][1] += a0 * q1; acc[0][2] += a0 * q2; acc[0][3] += a0 * q3;
      acc[1][0] += a1 * q0; acc[1][1] += a1 * q1; acc[1][2] += a1 * q2; acc[1][3] += a1 * q3;
      acc[2][0] += a2 * q0; acc[2][1] += a2 * q1; acc[2][2] += a2 * q2; acc[2][3] += a2 * q3;
      acc[3][0] += a3 * q0; acc[3][1] += a3 * q1; acc[3][2] += a3 * q2; acc[3][3] += a3 * q3;
    }
    __syncthreads();
  }
  size_t base = (size_t)dir * SQ * GD;
  #pragma unroll
  for (int i = 0; i < 4; ++i) {
    float4 v = make_float4(acc[i][0], acc[i][1], acc[i][2], acc[i][3]);
    *(float4*)&xproj[base + (size_t)(m0 + ty * 4 + i) * GD + n0 + tx * 4] = v;
  }
}

// ---------------- persistent bidirectional LSTM recurrence ----------------
// 32 blocks: 0..15 fwd, 16..31 rev; block owns 32 h (128 Whh rows).
// Protocol (r4-proven): one u64 per h per slot = (tag<<32)|h_bits, 8B agent
// atomics, double slot, monotone tags; overwrite-safety: seeing all tag-t
// words implies every block consumed slot (t-1), so publishing tag t+1 over
// tag t-1 words is safe.
// NEW intra-block structure: ONLY WAVE 0 POLLS -- thread l owns one 64B line
// (words 8l..8l+7, 8 pipelined atomic loads per round) -> 1 poller per L3
// line (was ~128), killing coherence-point queueing. Wave 0 stages h into
// LDS, lgkmcnt(0), releases via LDS flag; waves 1..7 spin on the LDS flag
// (no L3 traffic, no barrier). In-wave gates: per 16-lane group (h-index j):
// lanes kq=0 of gate g hold gx; all lanes apply activation via
// tanh(x)=2*sig(2x)-1 (one exp), gate lane gathers 4 values by shfl.
__global__ __launch_bounds__(512, 2) void lstm_kernel(const float* __restrict__ xproj,
    const float* __restrict__ Whh_f, const float* __restrict__ Whh_r,
    u64* __restrict__ payu, float* __restrict__ out) {
  __shared__ float hl[2][4 * 132];   // double-buffered h, quarter pitch 132
  __shared__ int hflag[2];
  int dir = blockIdx.x >> 4;
  int wid = blockIdx.x & 15;
  int hbase = wid * 32;
  int tid = threadIdx.x;
  int w = tid >> 6, l = tid & 63;
  int jl = l >> 4, gate = (l >> 2) & 3, kq = l & 3;
  int j = w * 4 + jl;                              // block-local h 0..31
  int Rrow = (gate << 9) + hbase + j;              // global gate row
  const float* Whh = dir ? Whh_r : Whh_f;
  const float* xp = xproj + (size_t)dir * SQ * GD;
  const f32x4* wsrc4 = (const f32x4*)(Whh + (size_t)Rrow * 512 + kq * 128);
  u64* mypay = payu + (size_t)dir * 1024;          // [slot][512]

  if (tid == 0) { hflag[0] = -1; hflag[1] = -1; }
  __syncthreads();

  const bool gl = (l & 15) == 0;                   // gate lane (gate=0,kq=0)
  const int base = l & 48;
  const int sq = l >> 4, so = (l & 15) * 8;        // stager LDS slot
  float cst = 0.f, hlast = 0.f;

  for (int t = 0; t < SQ; ++t) {
    int p = dir ? (SQ - 1 - t) : t;
    // weight + xval loads issued early: in flight during stage/spin
#define LDW(i) f32x4 w##i = wsrc4[i];
    REP32(LDW)
#undef LDW
    float xval = 0.f;
    if (kq == 0) xval = xp[(size_t)p * GD + Rrow];
    float* hbuf = hl[t & 1];
    if (w == 0) {
      // ---- stager wave: poll own 64B line, stage, release ----
      f32x4 h0, h1;
      if (t == 0) {
        h0 = (f32x4){0.f, 0.f, 0.f, 0.f}; h1 = h0;
      } else {
        const u64* src = mypay + ((t - 1) & 1) * 512 + l * 8;
        unsigned tg = (unsigned)t;
        u64 v[8];
        for (;;) {
          #pragma unroll
          for (int i = 0; i < 8; ++i)
            v[i] = __hip_atomic_load(src + i, __ATOMIC_RELAXED, __HIP_MEMORY_SCOPE_AGENT);
          bool ok = true;
          #pragma unroll
          for (int i = 0; i < 8; ++i) ok &= ((unsigned)(v[i] >> 32) == tg);
          if (ok) break;
        }
        h0[0] = __uint_as_float((unsigned)v[0]); h0[1] = __uint_as_float((unsigned)v[1]);
        h0[2] = __uint_as_float((unsigned)v[2]); h0[3] = __uint_as_float((unsigned)v[3]);
        h1[0] = __uint_as_float((unsigned)v[4]); h1[1] = __uint_as_float((unsigned)v[5]);
        h1[2] = __uint_as_float((unsigned)v[6]); h1[3] = __uint_as_float((unsigned)v[7]);
      }
      f32x4* d = (f32x4*)&hbuf[sq * 132 + so];
      d[0] = h0; d[1] = h1;
      asm volatile("s_waitcnt lgkmcnt(0)" ::: "memory");   // h writes before flag
      __hip_atomic_store(&hflag[t & 1], t, __ATOMIC_RELAXED, __HIP_MEMORY_SCOPE_WORKGROUP);
    } else {
      // ---- worker waves: spin on LDS flag (no L3 traffic) ----
      while (__hip_atomic_load(&hflag[t & 1], __ATOMIC_RELAXED, __HIP_MEMORY_SCOPE_WORKGROUP) < t) {}
    }
    // ---- GEMV over own kq quarter ----
    const f32x4* hq4 = (const f32x4*)&hbuf[kq * 132];
    float a0 = 0.f, a1 = 0.f, a2 = 0.f, a3 = 0.f;
#define GST(i) { f32x4 hh = hq4[i]; \
    a0 = fmaf(w##i[0], hh[0], a0); a1 = fmaf(w##i[1], hh[1], a1); \
    a2 = fmaf(w##i[2], hh[2], a2); a3 = fmaf(w##i[3], hh[3], a3); }
    REP32(GST)
#undef GST
    float acc = (a0 + a1) + (a2 + a3);
    acc += __shfl_xor(acc, 1);                     // kq reduce
    acc += __shfl_xor(acc, 2);
    float gx = acc + xval;                         // valid at kq==0 lanes
    // per-lane activation: gate 2 (g) tanh via 2*sig(2x)-1, others sigmoid
    float xin = (gate == 2) ? 2.f * gx : gx;
    float y = sigf(xin);
    float act = (gate == 2) ? fmaf(2.f, y, -1.f) : y;
    float aI = __shfl(act, base);                  // gather activated gates
    float aF = __shfl(act, base + 4);
    float aG = __shfl(act, base + 8);
    float aO = __shfl(act, base + 12);
    if (gl) {
      float c = aF * cst + aI * aG;
      float tc = fmaf(2.f, sigf(2.f * c), -1.f);   // tanh(c)
      float hval = aO * tc;
      cst = c; hlast = hval;
      u64 word = ((u64)(unsigned)(t + 1) << 32) | __float_as_uint(hval);
      __hip_atomic_store(mypay + (t & 1) * 512 + hbase + j, word,
                         __ATOMIC_RELAXED, __HIP_MEMORY_SCOPE_AGENT);
      out[(size_t)p * 1024 + dir * 512 + hbase + j] = hval;
    }
    // hl double-buffer: stager writes (t+1)&1 only after remote tag t+1 seen,
    // which implies every local wave published t -> done reading (t-1)&1.
  }
  if (gl) {
    size_t OH = (size_t)SQ * 1024;
    out[OH + dir * 512 + hbase + j] = hlast;       // hidden
    out[OH + 1024 + dir * 512 + hbase + j] = cst;  // cell
  }
}

extern "C" void kernel_launch(void* const* d_in, const int* in_sizes, int n_in,
                              void* d_out, int out_size, void* d_ws, size_t ws_size,
                              hipStream_t stream) {
  const float* wemb   = (const float*)d_in[0];
  const int*   cidx   = (const int*)d_in[1];
  const float* cemb   = (const float*)d_in[2];
  const float* conv_w = (const float*)d_in[3];
  const float* conv_b = (const float*)d_in[4];
  const float* lin_w  = (const float*)d_in[5];
  const float* lin_b  = (const float*)d_in[6];
  const float* Wih_f  = (const float*)d_in[7];
  const float* Whh_f  = (const float*)d_in[8];
  const float* bih_f  = (const float*)d_in[9];
  const float* bhh_f  = (const float*)d_in[10];
  const float* Wih_r  = (const float*)d_in[11];
  const float* Whh_r  = (const float*)d_in[12];
  const float* bih_r  = (const float*)d_in[13];
  const float* bhh_r  = (const float*)d_in[14];
  float* out = (float*)d_out;
  float* ws = (float*)d_ws;
  float* x     = ws + WS_X;
  float* xproj = ws + WS_XPROJ;
  float* Wt    = ws + WS_WT;
  float* linT  = ws + WS_LINT;
  float* sync  = ws + WS_SYNC;

  prep_kernel<<<768, 256, 0, stream>>>(conv_w, lin_w, Wt, linT, sync);
  charcnn_kernel<<<SQ, 256, 0, stream>>>(wemb, cidx, cemb, Wt, conv_b, linT, lin_b, x);
  xproj_kernel<<<dim3(64, 32, 2), 256, 0, stream>>>(x, Wih_f, Wih_r, bih_f, bhh_f, bih_r, bhh_r, xproj);
  lstm_kernel<<<32, 512, 0, stream>>>(xproj, Whh_f, Whh_r, (u64*)sync, out);
}

// Round 10
// 8396.877 us; speedup vs baseline: 2.4882x; 1.4911x over previous
//
#include <hip/hip_runtime.h>
#include <cstdint>

#define SQ 4096
#define FD 256
#define HD 512
#define GD 2048

// workspace layout (float elements)
#define WS_X       0                         // x [4096][512]
#define WS_XPROJ   (WS_X + SQ*HD)            // xproj [2][4096][2048]
#define WS_WT      (WS_XPROJ + 2*SQ*GD)      // conv_w transposed [2][256][256]
#define WS_LINT    (WS_WT + 2*FD*FD)         // lin_w transposed [256][256]
#define WS_SYNC    (WS_LINT + FD*FD)         // payload: u64[2][2][16][16][2] = 16 KB

typedef __attribute__((ext_vector_type(4))) float f32x4;
typedef unsigned long long u64;

__device__ __forceinline__ float sigf(float x) { return 1.f / (1.f + __expf(-x)); }
// tanh(x) = 2*sigmoid(2x) - 1  (one __expf; |err| ~1e-7)
__device__ __forceinline__ float tanh_s(float x) { return fmaf(2.f, sigf(2.f * x), -1.f); }

#define REP32(M) M(0)M(1)M(2)M(3)M(4)M(5)M(6)M(7)M(8)M(9)M(10)M(11)M(12)M(13)M(14)M(15) \
                 M(16)M(17)M(18)M(19)M(20)M(21)M(22)M(23)M(24)M(25)M(26)M(27)M(28)M(29)M(30)M(31)

// ---------------- prep: transpose small weights, zero sync payload ----------------
__global__ __launch_bounds__(256) void prep_kernel(const float* __restrict__ conv_w,
                                                   const float* __restrict__ lin_w,
                                                   float* __restrict__ Wt,
                                                   float* __restrict__ linT,
                                                   float* __restrict__ sync) {
  int n = blockIdx.x * 256 + threadIdx.x;
  if (n < 4096) sync[n] = 0.f;               // 16 KB payload (tags := 0)
  if (n < 2 * FD * FD) {
    int o = n & 255, f = (n >> 8) & 255, k = n >> 16;
    Wt[n] = conv_w[o * 512 + k * 256 + f];   // Wt[k][f][o]
  } else {
    int m = n - 2 * FD * FD;
    int o = m & 255, f = m >> 8;
    linT[m] = lin_w[o * 256 + f];            // linT[f][o]
  }
}

// ---------------- char CNN + concat into x ----------------
__global__ __launch_bounds__(256) void charcnn_kernel(const float* __restrict__ wemb,
    const int* __restrict__ cidx, const float* __restrict__ cemb,
    const float* __restrict__ Wt, const float* __restrict__ conv_b,
    const float* __restrict__ linT, const float* __restrict__ lin_b,
    float* __restrict__ x) {
  __shared__ float ceT[256][20];
  __shared__ float pooled[256];
  int s = blockIdx.x, o = threadIdx.x;
  #pragma unroll
  for (int l = 0; l < 16; ++l) {
    int idx = cidx[s * 16 + l];
    ceT[o][l] = cemb[idx * 256 + o];
  }
  __syncthreads();
  float acc[15];
  float cb = conv_b[o];
  #pragma unroll
  for (int l = 0; l < 15; ++l) acc[l] = cb;
  for (int f = 0; f < 256; ++f) {
    float w0 = Wt[f * 256 + o];
    float w1 = Wt[65536 + f * 256 + o];
    float4 ca = *(const float4*)&ceT[f][0];
    float4 cv = *(const float4*)&ceT[f][4];
    float4 cc = *(const float4*)&ceT[f][8];
    float4 cd = *(const float4*)&ceT[f][12];
    float c[16] = {ca.x, ca.y, ca.z, ca.w, cv.x, cv.y, cv.z, cv.w,
                   cc.x, cc.y, cc.z, cc.w, cd.x, cd.y, cd.z, cd.w};
    #pragma unroll
    for (int l = 0; l < 15; ++l) acc[l] += c[l] * w0 + c[l + 1] * w1;
  }
  float m = 0.f;
  #pragma unroll
  for (int l = 0; l < 15; ++l) m = fmaxf(m, acc[l]);
  pooled[o] = m;
  __syncthreads();
  float a2 = lin_b[o];
  for (int f = 0; f < 256; f += 4) {
    float4 p = *(const float4*)&pooled[f];
    a2 += p.x * linT[(f + 0) * 256 + o] + p.y * linT[(f + 1) * 256 + o]
        + p.z * linT[(f + 2) * 256 + o] + p.w * linT[(f + 3) * 256 + o];
  }
  x[(size_t)s * 512 + o] = wemb[(size_t)s * 256 + o];
  x[(size_t)s * 512 + 256 + o] = a2;
}

// ---------------- input projection GEMM ----------------
__global__ __launch_bounds__(256) void xproj_kernel(const float* __restrict__ x,
    const float* __restrict__ Wih_f, const float* __restrict__ Wih_r,
    const float* __restrict__ bih_f, const float* __restrict__ bhh_f,
    const float* __restrict__ bih_r, const float* __restrict__ bhh_r,
    float* __restrict__ xproj) {
  __shared__ float As[64][33];
  __shared__ float Bs[64][33];
  int dir = blockIdx.z;
  const float* B  = dir ? Wih_r : Wih_f;
  const float* b1 = dir ? bih_r : bih_f;
  const float* b2 = dir ? bhh_r : bhh_f;
  int m0 = blockIdx.x * 64, n0 = blockIdx.y * 64;
  int tid = threadIdx.x, tx = tid & 15, ty = tid >> 4;
  float acc[4][4];
  #pragma unroll
  for (int j = 0; j < 4; ++j) {
    float bias = b1[n0 + tx * 4 + j] + b2[n0 + tx * 4 + j];
    #pragma unroll
    for (int i = 0; i < 4; ++i) acc[i][j] = bias;
  }
  int lc = tid & 31, lr0 = tid >> 5;
  for (int k0 = 0; k0 < 512; k0 += 32) {
    #pragma unroll
    for (int i = 0; i < 8; ++i) {
      As[lr0 + 8 * i][lc] = x[(size_t)(m0 + lr0 + 8 * i) * 512 + k0 + lc];
      Bs[lr0 + 8 * i][lc] = B[(size_t)(n0 + lr0 + 8 * i) * 512 + k0 + lc];
    }
    __syncthreads();
    #pragma unroll
    for (int kk = 0; kk < 32; ++kk) {
      float a0 = As[ty * 4 + 0][kk], a1 = As[ty * 4 + 1][kk];
      float a2 = As[ty * 4 + 2][kk], a3 = As[ty * 4 + 3][kk];
      float q0 = Bs[tx * 4 + 0][kk], q1 = Bs[tx * 4 + 1][kk];
      float q2 = Bs[tx * 4 + 2][kk], q3 = Bs[tx * 4 + 3][kk];
      acc[0][0] += a0 * q0; acc[0][1] += a0 * q1; acc[0][2] += a0 * q2; acc[0][3] += a0 * q3;
      acc[1][0] += a1 * q0; acc[1][1] += a1 * q1; acc[1][2] += a1 * q2; acc[1][3] += a1 * q3;
      acc[2][0] += a2 * q0; acc[2][1] += a2 * q1; acc[2][2] += a2 * q2; acc[2][3] += a2 * q3;
      acc[3][0] += a3 * q0; acc[3][1] += a3 * q1; acc[3][2] += a3 * q2; acc[3][3] += a3 * q3;
    }
    __syncthreads();
  }
  size_t base = (size_t)dir * SQ * GD;
  #pragma unroll
  for (int i = 0; i < 4; ++i) {
    float4 v = make_float4(acc[i][0], acc[i][1], acc[i][2], acc[i][3]);
    *(float4*)&xproj[base + (size_t)(m0 + ty * 4 + i) * GD + n0 + tx * 4] = v;
  }
}

// ---------------- persistent bidirectional LSTM recurrence ----------------
// EXACT round-4 structure (best measured: 7.91 ms steady) with ONE change:
// the 32 loop-invariant f32x4 weight loads are PINNED into registers with
// empty asm ("+v") after the load, so the compiler cannot sink them into the
// loop (r4's VGPR_Count=88 proved it re-read 256 KB/CU/step through L1 --
// ~1.7 us/step, the dominant cost). Pressure ~188 VGPR < 256 cap at
// __launch_bounds__(512,2) -> resident, no spill.
// Protocol (proven r4): chunk = (tag,h0,h1,tag) as two u64 words, tag in each
// atomically-loaded word (no tearing, single round trip); per-lane publish
// words built from own register only; double-buffered slots; monotone tags.
__global__ __launch_bounds__(512, 2) void lstm_kernel(const float* __restrict__ xproj,
    const float* __restrict__ Whh_f, const float* __restrict__ Whh_r,
    u64* __restrict__ payu, float* __restrict__ out) {
  __shared__ float h4[4 * 132];   // h chunked by K-quarter, pitch 132
  __shared__ float g_lds[128];
  int dir = blockIdx.x >> 4;
  int wid = blockIdx.x & 15;
  int hbase = wid * 32;
  int tid = threadIdx.x;

  int r = tid >> 2, kq = tid & 3;                 // row 0..127, K-quarter
  int Rrow = ((r >> 5) << 9) + hbase + (r & 31);  // gate*512 + hbase + hoff
  const float* Whh = dir ? Whh_r : Whh_f;
  const float* xp = xproj + (size_t)dir * SQ * GD;
  const f32x4* wsrc4 = (const f32x4*)(Whh + (size_t)Rrow * 512 + kq * 128);
#define LDW(i) f32x4 w##i = wsrc4[i];
  REP32(LDW)
#undef LDW
  // pin: forbids sinking the loads into the loop (forces register residency)
#define PIN(i) asm volatile("" : "+v"(w##i));
  REP32(PIN)
#undef PIN

  int ib = tid >> 4, ic = tid & 15;               // reader: writer-block, chunk
  float cst = 0.f, hlast = 0.f;

  for (int t = 0; t < SQ; ++t) {
    int p = dir ? (SQ - 1 - t) : t;
    float xval = 0.f;
    if (kq == 0) xval = xp[(size_t)p * GD + Rrow];   // prefetch before poll
    if (tid < 256) {
      float v0, v1;
      if (t == 0) { v0 = 0.f; v1 = 0.f; }
      else {
        const u64* src = payu + ((((size_t)dir * 2 + ((t - 1) & 1)) * 16 + ib) * 16 + ic) * 2;
        unsigned tg = (unsigned)t;
        for (;;) {
          u64 lo = __hip_atomic_load(src,     __ATOMIC_RELAXED, __HIP_MEMORY_SCOPE_AGENT);
          u64 hi = __hip_atomic_load(src + 1, __ATOMIC_RELAXED, __HIP_MEMORY_SCOPE_AGENT);
          if ((unsigned)lo == tg && (unsigned)(hi >> 32) == tg) {
            v0 = __uint_as_float((unsigned)(lo >> 32));
            v1 = __uint_as_float((unsigned)hi);
            break;
          }
          __builtin_amdgcn_s_sleep(1);
        }
      }
      int ih = ib * 32 + ic * 2;
      h4[(ih >> 7) * 132 + (ih & 127)] = v0;
      int ih1 = ih + 1;
      h4[(ih1 >> 7) * 132 + (ih1 & 127)] = v1;
    }
    __syncthreads();                               // h ready
    float a0 = 0.f, a1 = 0.f, a2 = 0.f, a3 = 0.f;
    const f32x4* hq4 = (const f32x4*)&h4[kq * 132];
#define GST(i) { f32x4 hh = hq4[i]; \
    a0 = fmaf(w##i[0], hh[0], a0); a1 = fmaf(w##i[1], hh[1], a1); \
    a2 = fmaf(w##i[2], hh[2], a2); a3 = fmaf(w##i[3], hh[3], a3); }
    REP32(GST)
#undef GST
    float acc = (a0 + a1) + (a2 + a3);
    acc += __shfl_xor(acc, 1);
    acc += __shfl_xor(acc, 2);
    if (kq == 0) g_lds[r] = acc + xval;
    __syncthreads();                               // g ready
    if (tid < 32) {
      float ig = g_lds[tid], fg = g_lds[32 + tid], gg = g_lds[64 + tid], og = g_lds[96 + tid];
      float c = sigf(fg) * cst + sigf(ig) * tanh_s(gg);
      float hval = sigf(og) * tanh_s(c);
      cst = c; hlast = hval;
      out[(size_t)p * 1024 + dir * 512 + hbase + tid] = hval;
      // publish: each lane stores ONE u64 built from its OWN hval.
      unsigned tg = (unsigned)(t + 1);
      u64 word = (tid & 1) ? (((u64)tg << 32) | __float_as_uint(hval))
                           : (((u64)__float_as_uint(hval) << 32) | tg);
      u64* dst = payu + ((((size_t)dir * 2 + (t & 1)) * 16 + wid) * 16 + (tid >> 1)) * 2 + (tid & 1);
      __hip_atomic_store(dst, word, __ATOMIC_RELAXED, __HIP_MEMORY_SCOPE_AGENT);
    }
    // next iteration's h-ready barrier guards LDS reuse
  }
  if (tid < 32) {
    size_t OH = (size_t)SQ * 1024;
    out[OH + dir * 512 + hbase + tid] = hlast;           // hidden
    out[OH + 1024 + dir * 512 + hbase + tid] = cst;      // cell
  }
}

extern "C" void kernel_launch(void* const* d_in, const int* in_sizes, int n_in,
                              void* d_out, int out_size, void* d_ws, size_t ws_size,
                              hipStream_t stream) {
  const float* wemb   = (const float*)d_in[0];
  const int*   cidx   = (const int*)d_in[1];
  const float* cemb   = (const float*)d_in[2];
  const float* conv_w = (const float*)d_in[3];
  const float* conv_b = (const float*)d_in[4];
  const float* lin_w  = (const float*)d_in[5];
  const float* lin_b  = (const float*)d_in[6];
  const float* Wih_f  = (const float*)d_in[7];
  const float* Whh_f  = (const float*)d_in[8];
  const float* bih_f  = (const float*)d_in[9];
  const float* bhh_f  = (const float*)d_in[10];
  const float* Wih_r  = (const float*)d_in[11];
  const float* Whh_r  = (const float*)d_in[12];
  const float* bih_r  = (const float*)d_in[13];
  const float* bhh_r  = (const float*)d_in[14];
  float* out = (float*)d_out;
  float* ws = (float*)d_ws;
  float* x     = ws + WS_X;
  float* xproj = ws + WS_XPROJ;
  float* Wt    = ws + WS_WT;
  float* linT  = ws + WS_LINT;
  float* sync  = ws + WS_SYNC;

  prep_kernel<<<768, 256, 0, stream>>>(conv_w, lin_w, Wt, linT, sync);
  charcnn_kernel<<<SQ, 256, 0, stream>>>(wemb, cidx, cemb, Wt, conv_b, linT, lin_b, x);
  xproj_kernel<<<dim3(64, 32, 2), 256, 0, stream>>>(x, Wih_f, Wih_r, bih_f, bhh_f, bih_r, bhh_r, xproj);
  lstm_kernel<<<32, 512, 0, stream>>>(xproj, Whh_f, Whh_r, (u64*)sync, out);
}